// Round 13
// baseline (550.842 us; speedup 1.0000x reference)
//
#include <hip/hip_runtime.h>
#include <hip/hip_bf16.h>

// Hierarchical BiGRU. Round 23 = consolidation:
//  - gru_word reverted to the exact r20 body (97.1 us measured best).
//    r21 (register prefetch: spill) and r22 (LDS staging: +vmcnt drain,
//    +LDS reads) both regressed it -> gx latency was never the stall;
//    the compiler already overlaps the step-start loads with the MFMA
//    chain, and FETCH (81 of 154 MB) shows gx is ~half L2/L3-resident.
//  - gemm_word keeps r22's revOrd (fwd writes low-t tiles last; ~17 us
//    total gain attributed to it).
//  - prepack_all / sentence path / heads unchanged.

typedef __hip_bfloat16 bf16;
typedef _Float16 h16x8 __attribute__((ext_vector_type(8)));
typedef __fp16 fp16x2 __attribute__((ext_vector_type(2)));
typedef float f32x4 __attribute__((ext_vector_type(4)));

#define HDIM 200
#define NS   2560
#define TW   50
#define ND   256
#define DTR  10
#define VEMB 50000

#define GT   13
#define NT   39
#define NTP  40
#define KCH  7
#define HSTR 232
#define KC_W 10
#define KC_S 13

__device__ __forceinline__ float sigf(float x) {
    return __builtin_amdgcn_rcpf(1.f + __expf(-x));
}
__device__ __forceinline__ float tanh_fast(float x) {
    float e = __expf(2.f * x);
    return (e - 1.f) * __builtin_amdgcn_rcpf(e + 1.f);
}
__device__ __forceinline__ unsigned short f2h(float x) {
    union { _Float16 h; unsigned short u; } v;
    v.h = (_Float16)x;
    return v.u;
}
__device__ __forceinline__ float h2f(unsigned short u) {
    union { _Float16 h; unsigned short u; } v;
    v.u = u;
    return (float)v.h;
}
__device__ __forceinline__ unsigned pk2h(float a, float b) {
    union { fp16x2 p; unsigned u; } v;
    v.p = __builtin_amdgcn_cvt_pkrtz(a, b);
    return v.u;
}
__device__ __forceinline__ float hfsel(uint2 v, int rg) {
    unsigned u = (rg & 2) ? v.y : v.x;
    return h2f((unsigned short)((rg & 1) ? (u >> 16) : (u & 0xFFFFu)));
}

// ---------------- merged prepack: embh | whh | bih x4 | lens+bias ---------
#define PB_EMBH 12500
#define PB_WHH  (PB_EMBH + 273)
#define PB_BIH  (PB_WHH + 460)
#define PB_ALL  (PB_BIH + 20)

__global__ void prepack_all(
    const float* __restrict__ emb, unsigned short* __restrict__ embH,
    const float* __restrict__ whh0, const float* __restrict__ whh1,
    const float* __restrict__ whh2, const float* __restrict__ whh3,
    unsigned short* __restrict__ Bhh,
    const float* __restrict__ wih0, const float* __restrict__ wih1,
    const float* __restrict__ wih2, const float* __restrict__ wih3,
    unsigned short* __restrict__ BiW0, unsigned short* __restrict__ BiW1,
    unsigned short* __restrict__ BiS0, unsigned short* __restrict__ BiS1,
    const int* __restrict__ x, int* __restrict__ sl,
    const float* bi0, const float* bh0, const float* bi1, const float* bh1,
    const float* bi2, const float* bh2, const float* bi3, const float* bh3,
    float* __restrict__ bt)
{
    const int b = blockIdx.x;
    const int tid = threadIdx.x;

    if (b < PB_EMBH) {
        int gid = b * 256 + tid;
        int row = gid >> 6, c = gid & 63;
        if (c >= 40) return;
        int k0 = c * 8;
        unsigned short vals[8] __attribute__((aligned(16)));
        if (k0 + 7 < 300) {
            const float4 f0 = *reinterpret_cast<const float4*>(emb + (size_t)row * 300 + k0);
            const float4 f1 = *reinterpret_cast<const float4*>(emb + (size_t)row * 300 + k0 + 4);
            unsigned u0 = pk2h(f0.x, f0.y), u1 = pk2h(f0.z, f0.w);
            unsigned u2 = pk2h(f1.x, f1.y), u3 = pk2h(f1.z, f1.w);
            vals[0] = (unsigned short)u0; vals[1] = (unsigned short)(u0 >> 16);
            vals[2] = (unsigned short)u1; vals[3] = (unsigned short)(u1 >> 16);
            vals[4] = (unsigned short)u2; vals[5] = (unsigned short)(u2 >> 16);
            vals[6] = (unsigned short)u3; vals[7] = (unsigned short)(u3 >> 16);
        } else {
#pragma unroll
            for (int jj = 0; jj < 8; ++jj) {
                int k = k0 + jj;
                vals[jj] = (k < 300) ? f2h(emb[(size_t)row * 300 + k]) : (unsigned short)0;
            }
        }
        *reinterpret_cast<uint4*>(embH + (size_t)row * 320 + k0) =
            *reinterpret_cast<const uint4*>(vals);
        return;
    }

    if (b < PB_WHH) {
        int gid = (b - PB_EMBH) * 256 + tid;
        if (gid >= 4 * NT * KCH * 64) return;
        int lane = gid & 63;
        int f = gid >> 6;
        int kc = f % KCH;
        int tIdx = (f / KCH) % NT;
        int d = f / (KCH * NT);
        const float* w = (d == 0) ? whh0 : (d == 1) ? whh1 : (d == 2) ? whh2 : whh3;
        int g = tIdx / GT, j = tIdx % GT;
        int il = j * 16 + (lane & 15);
        int n = g * HDIM + il;
        int kb = kc * 32 + (lane >> 4) * 8;
        unsigned short vals[8] __attribute__((aligned(16)));
#pragma unroll
        for (int jj = 0; jj < 8; ++jj) {
            int k = kb + jj;
            float v = (il < HDIM && k < HDIM) ? w[n * HDIM + k] : 0.f;
            vals[jj] = f2h(v);
        }
        *reinterpret_cast<float4*>(reinterpret_cast<char*>(Bhh) + (size_t)gid * 16) =
            *reinterpret_cast<const float4*>(vals);
        return;
    }

    if (b < PB_BIH) {
        int rel = b - PB_WHH;
        const float* w; unsigned short* Bp; int Kin, KC, base;
        if (rel < 100)      { w = wih0; Bp = BiW0; Kin = 300; KC = KC_W; base = 0; }
        else if (rel < 200) { w = wih1; Bp = BiW1; Kin = 300; KC = KC_W; base = 100; }
        else if (rel < 330) { w = wih2; Bp = BiS0; Kin = 400; KC = KC_S; base = 200; }
        else                { w = wih3; Bp = BiS1; Kin = 400; KC = KC_S; base = 330; }
        int gid = (rel - base) * 256 + tid;
        if (gid >= NTP * KC * 64) return;
        int lane = gid & 63;
        int f = gid >> 6;
        int kc = f % KC;
        int tIdx = f / KC;
        int g = tIdx / GT, j = tIdx % GT;
        int il = j * 16 + (lane & 15);
        int n = g * HDIM + il;
        int kb = kc * 32 + (lane >> 4) * 8;
        unsigned short vals[8] __attribute__((aligned(16)));
#pragma unroll
        for (int jj = 0; jj < 8; ++jj) {
            int k = kb + jj;
            float v = (tIdx < NT && il < HDIM && k < Kin) ? w[n * Kin + k] : 0.f;
            vals[jj] = f2h(v);
        }
        *reinterpret_cast<float4*>(reinterpret_cast<char*>(Bp) + (size_t)gid * 16) =
            *reinterpret_cast<const float4*>(vals);
        return;
    }

    {
        int gid = (b - PB_BIH) * 256 + tid;
        if (gid < NS) {
            int c = 0;
            for (int t = 0; t < TW; ++t) c += (x[gid * TW + t] != 0) ? 1 : 0;
            sl[gid] = c;
            return;
        }
        int g2 = gid - NS;
        if (g2 >= 4 * 624) return;
        int d = g2 / 624, col = g2 % 624;
        int g = col / 208, i = col % 208;
        const float* bi = (d == 0) ? bi0 : (d == 1) ? bi1 : (d == 2) ? bi2 : bi3;
        const float* bh = (d == 0) ? bh0 : (d == 1) ? bh1 : (d == 2) ? bh2 : bh3;
        float v = 0.f;
        if (i < HDIM) v = (g < 2) ? (bi[g * HDIM + i] + bh[g * HDIM + i]) : bi[2 * HDIM + i];
        bt[g2] = v;
    }
}

// ---------------- word-level MFMA GEMM: 64-row blocks, 2/CU ---------------
// revOrd=1 reverses block order so low-t tiles are written LAST (L3-fresh
// for the fwd gru that reads t=0 first).
__global__ __launch_bounds__(512, 4) void gemm_word(
    const unsigned short* __restrict__ embH, const int* __restrict__ idx,
    const unsigned short* __restrict__ Bp,
    const float* __restrict__ bt, unsigned short* __restrict__ gxOut, int revOrd)
{
    __shared__ __align__(16) unsigned short As[64 * 320];  // 40 KB

    const int tid = threadIdx.x;
    const int n_w = tid >> 6, lane = tid & 63;
    const int bm = revOrd ? (gridDim.x - 1 - blockIdx.x) : blockIdx.x;

    {
        const int srow = tid >> 3, q8 = tid & 7;
        int rp = bm * 64 + srow;
        int tok = idx[(rp % NS) * TW + (rp / NS)];
        const unsigned short* src = embH + (size_t)tok * 320;
        const int rx = srow & 7;
        unsigned short* dst = &As[srow * 320];
#pragma unroll
        for (int jj = 0; jj < 5; ++jj) {
            int c = q8 + jj * 8;                    // chunk 0..39
            uint4 v = *reinterpret_cast<const uint4*>(src + c * 8);
            int slot = c ^ rx;
            *reinterpret_cast<uint4*>(dst + slot * 8) = v;
        }
    }
    __syncthreads();

    f32x4 acc[4][5];
#pragma unroll
    for (int i = 0; i < 4; ++i)
#pragma unroll
        for (int j = 0; j < 5; ++j) acc[i][j] = (f32x4){0.f, 0.f, 0.f, 0.f};

    const uint4* bq = reinterpret_cast<const uint4*>(Bp);
    const int q = lane >> 4, r15 = lane & 15;
    const int sx = r15 & 7;

#pragma unroll 2
    for (int kc = 0; kc < KC_W; ++kc) {
        h16x8 ah[4];
        const int slot = (kc * 4 + q) ^ sx;
#pragma unroll
        for (int mt = 0; mt < 4; ++mt)
            ah[mt] = *reinterpret_cast<const h16x8*>(
                &As[(mt * 16 + r15) * 320 + slot * 8]);
        uint4 b[5];
#pragma unroll
        for (int j = 0; j < 5; ++j) {
            int gnt = n_w * 5 + j;
            b[j] = bq[(size_t)(gnt * KC_W + kc) * 64 + lane];
        }
#pragma unroll
        for (int mt = 0; mt < 4; ++mt)
#pragma unroll
            for (int j = 0; j < 5; ++j)
                acc[mt][j] = __builtin_amdgcn_mfma_f32_16x16x32_f16(
                    ah[mt], *reinterpret_cast<const h16x8*>(&b[j]),
                    acc[mt][j], 0, 0, 0);
    }

    float btv[5];
#pragma unroll
    for (int j = 0; j < 5; ++j) {
        int gnt = n_w * 5 + j;
        btv[j] = (gnt < NT) ? bt[gnt * 16 + r15] : 0.f;
    }

#pragma unroll
    for (int mt = 0; mt < 4; ++mt) {
        int gmt = bm * 4 + mt;
#pragma unroll
        for (int j = 0; j < 5; ++j) {
            int gnt = n_w * 5 + j;
            if (gnt < NT) {
                uint2 v;
                v.x = pk2h(acc[mt][j][0] + btv[j], acc[mt][j][1] + btv[j]);
                v.y = pk2h(acc[mt][j][2] + btv[j], acc[mt][j][3] + btv[j]);
                *reinterpret_cast<uint2*>(reinterpret_cast<char*>(gxOut) +
                    ((size_t)(gmt * NT + gnt) * 64 + lane) * 8) = v;
            }
        }
    }
}

// ---------------- sentence-level MFMA GEMM, both directions (f32 A) -------
__global__ __launch_bounds__(512, 2) void gemm_sent(
    const float* __restrict__ Afl, int astride,
    const unsigned short* __restrict__ Bp0, const unsigned short* __restrict__ Bp1,
    const float* __restrict__ bt0, const float* __restrict__ bt1,
    unsigned short* __restrict__ gx0, unsigned short* __restrict__ gx1, int nF)
{
    __shared__ __align__(16) unsigned short As[2][128 * 32];  // 16 KB dbuf

    const int tid = threadIdx.x;
    const int wv = tid >> 6, lane = tid & 63;
    const int d = (blockIdx.x >= nF) ? 1 : 0;
    const int bm = d ? (blockIdx.x - nF) : blockIdx.x;
    const unsigned short* Bp = d ? Bp1 : Bp0;
    const float* bt = d ? bt1 : bt0;
    unsigned short* gxOut = d ? gx1 : gx0;
    const int m_w = wv & 1, n_w = wv >> 1;

    int aaddr[4];
#pragma unroll
    for (int mt = 0; mt < 4; ++mt) {
        int row = m_w * 64 + mt * 16 + (lane & 15);
        aaddr[mt] = row * 32 + (((lane >> 4) ^ ((row >> 1) & 3)) << 3);
    }

    const int srow = tid >> 2, qk = tid & 3;
    const int ssw = (srow >> 1) & 3;

    f32x4 acc[4][10];
#pragma unroll
    for (int i = 0; i < 4; ++i)
#pragma unroll
        for (int j = 0; j < 10; ++j) acc[i][j] = (f32x4){0.f, 0.f, 0.f, 0.f};

    const uint4* bq = reinterpret_cast<const uint4*>(Bp);
    const float* arow = Afl + (size_t)(bm * 128 + srow) * astride + qk * 8;

    float4 f[2], fn[2];
#pragma unroll
    for (int j = 0; j < 2; ++j)
        f[j] = *reinterpret_cast<const float4*>(arow + j * 4);

    for (int kc = 0; kc < KC_S; ++kc) {
        unsigned short* Ab = &As[kc & 1][0];
        {
            uint4 vh;
            vh.x = pk2h(f[0].x, f[0].y);
            vh.y = pk2h(f[0].z, f[0].w);
            vh.z = pk2h(f[1].x, f[1].y);
            vh.w = pk2h(f[1].z, f[1].w);
            int slot = qk ^ ssw;
            *reinterpret_cast<uint4*>(&Ab[srow * 32 + slot * 8]) = vh;
        }
        __syncthreads();

        if (kc + 1 < KC_S) {
#pragma unroll
            for (int j = 0; j < 2; ++j)
                fn[j] = *reinterpret_cast<const float4*>(arow + (kc + 1) * 32 + j * 4);
        }

        h16x8 ah[4];
#pragma unroll
        for (int mt = 0; mt < 4; ++mt)
            ah[mt] = *reinterpret_cast<const h16x8*>(&Ab[aaddr[mt]]);

#pragma unroll
        for (int half = 0; half < 2; ++half) {
            uint4 b[5];
#pragma unroll
            for (int j = 0; j < 5; ++j) {
                int gnt = n_w * 10 + half * 5 + j;
                b[j] = bq[(size_t)(gnt * KC_S + kc) * 64 + lane];
            }
#pragma unroll
            for (int mt = 0; mt < 4; ++mt)
#pragma unroll
                for (int j = 0; j < 5; ++j)
                    acc[mt][half * 5 + j] = __builtin_amdgcn_mfma_f32_16x16x32_f16(
                        ah[mt], *reinterpret_cast<const h16x8*>(&b[j]),
                        acc[mt][half * 5 + j], 0, 0, 0);
        }
        if (kc + 1 < KC_S) { f[0] = fn[0]; f[1] = fn[1]; }
    }

    float btv[10];
#pragma unroll
    for (int j = 0; j < 10; ++j) {
        int gnt = n_w * 10 + j;
        btv[j] = (gnt < NT) ? bt[gnt * 16 + (lane & 15)] : 0.f;
    }

#pragma unroll
    for (int mt = 0; mt < 4; ++mt) {
        int gmt = bm * 8 + m_w * 4 + mt;
#pragma unroll
        for (int j = 0; j < 10; ++j) {
            int gnt = n_w * 10 + j;
            if (gnt < NT) {
                uint2 v;
                v.x = pk2h(acc[mt][j][0] + btv[j], acc[mt][j][1] + btv[j]);
                v.y = pk2h(acc[mt][j][2] + btv[j], acc[mt][j][3] + btv[j]);
                *reinterpret_cast<uint2*>(reinterpret_cast<char*>(gxOut) +
                    ((size_t)(gmt * NT + gnt) * 64 + lane) * 8) = v;
            }
        }
    }
}

// ---------------- word GRU: 7 waves x 2 tiles/wave (r20 body) -------------
__global__ __launch_bounds__(448, 2) void gru_word(
    const unsigned short* __restrict__ gxA, const unsigned short* __restrict__ gxB,
    const unsigned short* __restrict__ Bp, int dirBase0, int dirBase1,
    const float* __restrict__ bh0, const float* __restrict__ bh1,
    const int* __restrict__ lens, float* __restrict__ pool,
    int S, int T, int poolMode, int nF)
{
    __shared__ __align__(16) unsigned short hh[2][16 * HSTR];  // 14.5 KB

    const int dsel = (blockIdx.x >= nF) ? 1 : 0;
    const int lb = dsel ? (blockIdx.x - nF) : blockIdx.x;
    const unsigned short* gx = dsel ? gxB : gxA;
    const int dirBase = dsel ? dirBase1 : dirBase0;
    const float* bh = dsel ? bh1 : bh0;
    const int dirOff = dsel ? HDIM : 0;
    const int rev = dsel;

    const int tid = threadIdx.x;
    const int w = tid >> 6, lane = tid & 63;
    const int quad = lane >> 4, c = lane & 15;
    const int row0 = lb * 16;
    const int j0 = 2 * w, j1 = 2 * w + 1;
    const int i0 = j0 * 16 + c, i1 = j1 * 16 + c;
    const bool t1v = (j1 < GT);             // wave-uniform
    const bool iv0 = (i0 < HDIM), iv1 = t1v && (i1 < HDIM);

    for (int p = tid; p < 2 * 16 * HSTR; p += 448)
        hh[0][p] = 0;                        // zero both buffers (flat)
    __syncthreads();

    const float bhn0 = iv0 ? bh[2 * HDIM + i0] : 0.f;
    const float bhn1 = iv1 ? bh[2 * HDIM + i1] : 0.f;

    int slen[4];
    float hr0[4], hr1[4], pa0[4], pa1[4];
#pragma unroll
    for (int rg = 0; rg < 4; ++rg) {
        int L = lens[row0 + quad * 4 + rg];
        if (L < 0) L = 0;
        if (L > T) L = T;
        slen[rg] = L;
        hr0[rg] = 0.f; hr1[rg] = 0.f; pa0[rg] = 0.f; pa1[rg] = 0.f;
    }

    const float4* Bq = reinterpret_cast<const float4*>(Bp);
    h16x8 bfr[2][3][KCH];
#pragma unroll
    for (int g = 0; g < 3; ++g)
#pragma unroll
        for (int kc = 0; kc < KCH; ++kc) {
            {
                int fidx = (dirBase + g * GT + j0) * KCH + kc;
                float4 raw = Bq[(size_t)fidx * 64 + lane];
                bfr[0][g][kc] = *reinterpret_cast<h16x8*>(&raw);
            }
            if (t1v) {
                int fidx = (dirBase + g * GT + j1) * KCH + kc;
                float4 raw = Bq[(size_t)fidx * 64 + lane];
                bfr[1][g][kc] = *reinterpret_cast<h16x8*>(&raw);
            }
        }

    const char* gxb = reinterpret_cast<const char*>(gx);
    const int am = c * HSTR + quad * 8;
    const int SG = S >> 4;
    const int hw0 = (quad * 4) * HSTR + i0;
    const int hw1 = (quad * 4) * HSTR + i1;
    const int dstep = (rev ? -SG : SG) * NT * 512;
    int boff;
    {
        const int t0 = rev ? (T - 1) : 0;
        boff = ((t0 * SG + lb) * NT) * 512 + lane * 8;
    }
    __syncthreads();

    for (int ts = 0; ts < T; ++ts) {
        const int t = rev ? (T - 1 - ts) : ts;
        const int cur = ts & 1, nxt = cur ^ 1;

        // gx for this step (issued at step start; latency overlaps MFMA)
        uint2 gx0[3], gx1[3];
#pragma unroll
        for (int g = 0; g < 3; ++g) {
            gx0[g] = *reinterpret_cast<const uint2*>(gxb + boff + (g * GT + j0) * 512);
            if (t1v)
                gx1[g] = *reinterpret_cast<const uint2*>(gxb + boff + (g * GT + j1) * 512);
        }
        boff += dstep;

        f32x4 a00 = (f32x4){0.f, 0.f, 0.f, 0.f}, a01 = a00, a02 = a00;
        f32x4 a10 = a00, a11 = a00, a12 = a00;
#pragma unroll
        for (int kc = 0; kc < KCH; ++kc) {
            h16x8 ah = *reinterpret_cast<const h16x8*>(&hh[cur][am + kc * 32]);
            a00 = __builtin_amdgcn_mfma_f32_16x16x32_f16(ah, bfr[0][0][kc], a00, 0, 0, 0);
            a01 = __builtin_amdgcn_mfma_f32_16x16x32_f16(ah, bfr[0][1][kc], a01, 0, 0, 0);
            a02 = __builtin_amdgcn_mfma_f32_16x16x32_f16(ah, bfr[0][2][kc], a02, 0, 0, 0);
            if (t1v) {
                a10 = __builtin_amdgcn_mfma_f32_16x16x32_f16(ah, bfr[1][0][kc], a10, 0, 0, 0);
                a11 = __builtin_amdgcn_mfma_f32_16x16x32_f16(ah, bfr[1][1][kc], a11, 0, 0, 0);
                a12 = __builtin_amdgcn_mfma_f32_16x16x32_f16(ah, bfr[1][2][kc], a12, 0, 0, 0);
            }
        }

        if (iv0) {
#pragma unroll
            for (int rg = 0; rg < 4; ++rg) {
                float r = sigf(hfsel(gx0[0], rg) + a00[rg]);
                float z = sigf(hfsel(gx0[1], rg) + a01[rg]);
                float n = tanh_fast(hfsel(gx0[2], rg) + r * (a02[rg] + bhn0));
                float hnew = n + z * (hr0[rg] - n);
                hr0[rg] = hnew;
                hh[nxt][hw0 + rg * HSTR] = f2h(hnew);
                pa0[rg] += (t < slen[rg]) ? hnew : 0.f;
            }
        }
        if (iv1) {
#pragma unroll
            for (int rg = 0; rg < 4; ++rg) {
                float r = sigf(hfsel(gx1[0], rg) + a10[rg]);
                float z = sigf(hfsel(gx1[1], rg) + a11[rg]);
                float n = tanh_fast(hfsel(gx1[2], rg) + r * (a12[rg] + bhn1));
                float hnew = n + z * (hr1[rg] - n);
                hr1[rg] = hnew;
                hh[nxt][hw1 + rg * HSTR] = f2h(hnew);
                pa1[rg] += (t < slen[rg]) ? hnew : 0.f;
            }
        }
        __syncthreads();
    }

#pragma unroll
    for (int rg = 0; rg < 4; ++rg) {
        int sg = row0 + quad * 4 + rg;
        int L = slen[rg];
        int prow = poolMode ? ((sg % 10) * ND + sg / 10) : sg;
        float inv = (L > 0) ? 1.f / (float)L : 0.f;
        if (iv0) pool[(size_t)prow * 400 + dirOff + i0] = pa0[rg] * inv;
        if (iv1) pool[(size_t)prow * 400 + dirOff + i1] = pa1[rg] * inv;
    }
}

// ---------------- sentence GRU: proven 13-wave kernel ---------------------
__global__ __launch_bounds__(832, 4) void gru_fused(
    const unsigned short* __restrict__ gxA, const unsigned short* __restrict__ gxB,
    const unsigned short* __restrict__ Bp, int dirBase0, int dirBase1,
    const float* __restrict__ bh0, const float* __restrict__ bh1,
    const int* __restrict__ lens, float* __restrict__ pool,
    int S, int T, int poolMode, int nF)
{
    __shared__ __align__(16) unsigned short hh[2][16 * HSTR];  // 14.5 KB

    const int dsel = (blockIdx.x >= nF) ? 1 : 0;
    const int lb = dsel ? (blockIdx.x - nF) : blockIdx.x;
    const unsigned short* gx = dsel ? gxB : gxA;
    const int dirBase = dsel ? dirBase1 : dirBase0;
    const float* bh = dsel ? bh1 : bh0;
    const int dirOff = dsel ? HDIM : 0;
    const int rev = dsel;

    const int tid = threadIdx.x;
    const int w = tid >> 6, lane = tid & 63;
    const int quad = lane >> 4, c = lane & 15;
    const int row0 = lb * 16;
    const int i = w * 16 + c;
    const bool iv = (i < HDIM);

    for (int p = tid; p < 16 * HSTR; p += 832) { hh[0][p] = 0; hh[1][p] = 0; }
    __syncthreads();

    const float bhn = iv ? bh[2 * HDIM + i] : 0.f;

    int slen[4];
    float hreg[4], pacc[4];
#pragma unroll
    for (int rg = 0; rg < 4; ++rg) {
        int L = lens[row0 + quad * 4 + rg];
        if (L < 0) L = 0;
        if (L > T) L = T;
        slen[rg] = L;
        hreg[rg] = 0.f; pacc[rg] = 0.f;
    }

    const float4* Bq = reinterpret_cast<const float4*>(Bp);
    h16x8 bfr[3][7];
#pragma unroll
    for (int g = 0; g < 3; ++g)
#pragma unroll
        for (int kc = 0; kc < KCH; ++kc) {
            int fidx = (dirBase + g * GT + w) * KCH + kc;
            float4 raw = Bq[(size_t)fidx * 64 + lane];
            bfr[g][kc] = *reinterpret_cast<h16x8*>(&raw);
        }

    const char* gxb = reinterpret_cast<const char*>(gx);
    const int am = c * HSTR + quad * 8;
    const int SG = S >> 4;
    const int hw0 = (quad * 4) * HSTR + i;
    const int GSTR = GT * 64 * 8;
    const int dstep = (rev ? -SG : SG) * NT * 512;
    __syncthreads();

    uint2 gxv[3], gnx[3];
    int boff;
    {
        const int t0 = rev ? (T - 1) : 0;
        boff = (((t0 * SG + lb) * NT + w) * 64 + lane) * 8;
#pragma unroll
        for (int g = 0; g < 3; ++g)
            gxv[g] = *reinterpret_cast<const uint2*>(gxb + boff + g * GSTR);
        boff += dstep;
    }

    for (int ts = 0; ts < T; ++ts) {
        const int t = rev ? (T - 1 - ts) : ts;
        const int cur = ts & 1, nxt = cur ^ 1;

        if (ts + 1 < T) {
#pragma unroll
            for (int g = 0; g < 3; ++g)
                gnx[g] = *reinterpret_cast<const uint2*>(gxb + boff + g * GSTR);
            boff += dstep;
        }

        f32x4 a0 = (f32x4){0.f, 0.f, 0.f, 0.f}, a1 = a0, a2 = a0;
#pragma unroll
        for (int kc = 0; kc < KCH; ++kc) {
            h16x8 ah = *reinterpret_cast<const h16x8*>(&hh[cur][am + kc * 32]);
            a0 = __builtin_amdgcn_mfma_f32_16x16x32_f16(ah, bfr[0][kc], a0, 0, 0, 0);
            a1 = __builtin_amdgcn_mfma_f32_16x16x32_f16(ah, bfr[1][kc], a1, 0, 0, 0);
            a2 = __builtin_amdgcn_mfma_f32_16x16x32_f16(ah, bfr[2][kc], a2, 0, 0, 0);
        }

        if (iv) {
#pragma unroll
            for (int rg = 0; rg < 4; ++rg) {
                float xr = hfsel(gxv[0], rg);
                float xz = hfsel(gxv[1], rg);
                float xn = hfsel(gxv[2], rg);
                float r = sigf(xr + a0[rg]);
                float z = sigf(xz + a1[rg]);
                float n = tanh_fast(xn + r * (a2[rg] + bhn));
                float hnew = n + z * (hreg[rg] - n);
                hreg[rg] = hnew;
                hh[nxt][hw0 + rg * HSTR] = f2h(hnew);
                pacc[rg] += (t < slen[rg]) ? hnew : 0.f;
            }
        }
        __syncthreads();
        if (ts + 1 < T) {
#pragma unroll
            for (int g = 0; g < 3; ++g) gxv[g] = gnx[g];
        }
    }

    if (iv) {
#pragma unroll
        for (int rg = 0; rg < 4; ++rg) {
            int sg = row0 + quad * 4 + rg;
            int L = slen[rg];
            float v = (L > 0) ? pacc[rg] / (float)L : 0.f;
            int prow = poolMode ? ((sg % 10) * ND + sg / 10) : sg;
            pool[(size_t)prow * 400 + dirOff + i] = v;
        }
    }
}

// ---------------- heads: 256 blocks x 1 wave ----------------
__global__ __launch_bounds__(64) void head_kernel(
    const float* __restrict__ d_pool, const int* __restrict__ doc_lens,
    const float* __restrict__ doc_w, const float* __restrict__ doc_b,
    const float* __restrict__ sent_w, const float* __restrict__ sent_b,
    float* __restrict__ out)
{
    const int d = blockIdx.x;
    const int lane = threadIdx.x;

    int part = 0;
#pragma unroll
    for (int rep = 0; rep < 4; ++rep) {
        int j = lane + rep * 64;
        int v = doc_lens[j];
        v = (v < 0) ? 0 : (v > DTR ? DTR : v);
        if (j < d) part += v;
    }
#pragma unroll
    for (int off = 32; off; off >>= 1) part += __shfl_down(part, off);
    int soff = __shfl(part, 0);

    int dl = doc_lens[d];
    dl = (dl < 0) ? 0 : (dl > DTR ? DTR : dl);
    const float* dv = d_pool + (size_t)d * 400;

    for (int o = 0; o <= dl; ++o) {
        const float* wrow = (o == 0) ? doc_w : sent_w + (o - 1) * 400;
        float s = 0.f;
        for (int f = lane; f < 400; f += 64) s += dv[f] * wrow[f];
#pragma unroll
        for (int off = 32; off; off >>= 1) s += __shfl_down(s, off);
        if (lane == 0) {
            float bias = (o == 0) ? doc_b[0] : sent_b[o - 1];
            out[(o == 0) ? d : (ND + soff + (o - 1))] = sigf(s + bias);
        }
    }
}

// --------------------------------------------------------------------------
extern "C" void kernel_launch(void* const* d_in, const int* in_sizes, int n_in,
                              void* d_out, int out_size, void* d_ws, size_t ws_size,
                              hipStream_t stream) {
    const int*   x        = (const int*)d_in[0];
    const int*   doc_lens = (const int*)d_in[2];
    const float* emb      = (const float*)d_in[3];
    const float* wf_ih = (const float*)d_in[4];
    const float* wf_hh = (const float*)d_in[5];
    const float* wf_bi = (const float*)d_in[6];
    const float* wf_bh = (const float*)d_in[7];
    const float* wb_ih = (const float*)d_in[8];
    const float* wb_hh = (const float*)d_in[9];
    const float* wb_bi = (const float*)d_in[10];
    const float* wb_bh = (const float*)d_in[11];
    const float* sf_ih = (const float*)d_in[12];
    const float* sf_hh = (const float*)d_in[13];
    const float* sf_bi = (const float*)d_in[14];
    const float* sf_bh = (const float*)d_in[15];
    const float* sb_ih = (const float*)d_in[16];
    const float* sb_hh = (const float*)d_in[17];
    const float* sb_bi = (const float*)d_in[18];
    const float* sb_bh = (const float*)d_in[19];
    const float* doc_w  = (const float*)d_in[20];
    const float* doc_b  = (const float*)d_in[21];
    const float* sent_w = (const float*)d_in[22];
    const float* sent_b = (const float*)d_in[23];

    const size_t GXSZ = 159744000;   // full-range gx
    char* ws = (char*)d_ws;
    const size_t base = GXSZ;

    unsigned short* gxF  = (unsigned short*)(ws);
    unsigned short* gxS0 = (unsigned short*)(ws);            // sentence slices
    unsigned short* gxS1 = (unsigned short*)(ws + 8000000);
    float* s_in   = (float*)(ws + base);                       // 4,096,256 B
    float* dpool  = (float*)(ws + base + 4096256);             // 409,600 B
    int*   sl     = (int*)(ws + base + 4096256 + 409600);      // 10,240 B
    unsigned short* Bhh  = (unsigned short*)(ws + base + 4096256 + 409600 + 10240);
    unsigned short* BiW0 = (unsigned short*)((char*)Bhh + 1118208);
    unsigned short* BiW1 = BiW0 + NTP * KC_W * 64 * 8;
    unsigned short* BiS0 = (unsigned short*)((char*)BiW0 + 819200);
    unsigned short* BiS1 = BiS0 + NTP * KC_S * 64 * 8;
    float* bt     = (float*)((char*)BiS0 + 1064960);
    unsigned short* embH = (unsigned short*)((char*)bt + 9984);   // 32,000,000

    prepack_all<<<PB_ALL, 256, 0, stream>>>(
        emb, embH,
        wf_hh, wb_hh, sf_hh, sb_hh, Bhh,
        wf_ih, wb_ih, sf_ih, sb_ih, BiW0, BiW1, BiS0, BiS1,
        x, sl,
        wf_bi, wf_bh, wb_bi, wb_bh, sf_bi, sf_bh, sb_bi, sb_bh, bt);

    // word level, sequential directions
    gemm_word<<<2000, 512, 0, stream>>>(embH, x, BiW0, bt + 0, gxF, 1);   // fwd: low t last
    gru_word<<<160, 448, 0, stream>>>(
        gxF, gxF, Bhh, 0 * NT, 1 * NT, wf_bh, wb_bh, sl, s_in, NS, TW, 1, 160);
    gemm_word<<<2000, 512, 0, stream>>>(embH, x, BiW1, bt + 624, gxF, 0); // bwd: high t last
    gru_word<<<160, 448, 0, stream>>>(
        gxF, gxF, Bhh, 0 * NT, 1 * NT, wf_bh, wb_bh, sl, s_in, NS, TW, 1, 0);

    // sentence level: direction-fused (proven 13-wave kernel)
    gemm_sent<<<40, 512, 0, stream>>>(
        s_in, 400, BiS0, BiS1, bt + 2 * 624, bt + 3 * 624, gxS0, gxS1, 20);
    gru_fused<<<32, 832, 0, stream>>>(
        gxS0, gxS1, Bhh, 2 * NT, 3 * NT, sf_bh, sb_bh, doc_lens, dpool, ND, DTR, 0, 16);

    head_kernel<<<ND, 64, 0, stream>>>(dpool, doc_lens, doc_w, doc_b, sent_w, sent_b, (float*)d_out);
}

// Round 14
// 537.587 us; speedup vs baseline: 1.0247x; 1.0247x over previous
//
#include <hip/hip_runtime.h>
#include <hip/hip_bf16.h>

// Hierarchical BiGRU. Round 24 = r23 + gemm_sent ported to the proven
// single-barrier structure (the last kernel on the old 13-barrier
// template). 64-row blocks (80 dual-dir, one round over CUs), whole
// 64x448-half A-panel staged with f32->f16 convert + XOR swizzle, ONE
// barrier, then a barrier-free 13-kc MFMA sweep (acc[4][5]).
// Everything else byte-identical to r23 (550.8 us consolidated best:
// gru_word r20 body 97 us x2, gemm_word 64-row + revOrd, prepack_all).

typedef __hip_bfloat16 bf16;
typedef _Float16 h16x8 __attribute__((ext_vector_type(8)));
typedef __fp16 fp16x2 __attribute__((ext_vector_type(2)));
typedef float f32x4 __attribute__((ext_vector_type(4)));

#define HDIM 200
#define NS   2560
#define TW   50
#define ND   256
#define DTR  10
#define VEMB 50000

#define GT   13
#define NT   39
#define NTP  40
#define KCH  7
#define HSTR 232
#define KC_W 10
#define KC_S 13

__device__ __forceinline__ float sigf(float x) {
    return __builtin_amdgcn_rcpf(1.f + __expf(-x));
}
__device__ __forceinline__ float tanh_fast(float x) {
    float e = __expf(2.f * x);
    return (e - 1.f) * __builtin_amdgcn_rcpf(e + 1.f);
}
__device__ __forceinline__ unsigned short f2h(float x) {
    union { _Float16 h; unsigned short u; } v;
    v.h = (_Float16)x;
    return v.u;
}
__device__ __forceinline__ float h2f(unsigned short u) {
    union { _Float16 h; unsigned short u; } v;
    v.u = u;
    return (float)v.h;
}
__device__ __forceinline__ unsigned pk2h(float a, float b) {
    union { fp16x2 p; unsigned u; } v;
    v.p = __builtin_amdgcn_cvt_pkrtz(a, b);
    return v.u;
}
__device__ __forceinline__ float hfsel(uint2 v, int rg) {
    unsigned u = (rg & 2) ? v.y : v.x;
    return h2f((unsigned short)((rg & 1) ? (u >> 16) : (u & 0xFFFFu)));
}

// ---------------- merged prepack: embh | whh | bih x4 | lens+bias ---------
#define PB_EMBH 12500
#define PB_WHH  (PB_EMBH + 273)
#define PB_BIH  (PB_WHH + 460)
#define PB_ALL  (PB_BIH + 20)

__global__ void prepack_all(
    const float* __restrict__ emb, unsigned short* __restrict__ embH,
    const float* __restrict__ whh0, const float* __restrict__ whh1,
    const float* __restrict__ whh2, const float* __restrict__ whh3,
    unsigned short* __restrict__ Bhh,
    const float* __restrict__ wih0, const float* __restrict__ wih1,
    const float* __restrict__ wih2, const float* __restrict__ wih3,
    unsigned short* __restrict__ BiW0, unsigned short* __restrict__ BiW1,
    unsigned short* __restrict__ BiS0, unsigned short* __restrict__ BiS1,
    const int* __restrict__ x, int* __restrict__ sl,
    const float* bi0, const float* bh0, const float* bi1, const float* bh1,
    const float* bi2, const float* bh2, const float* bi3, const float* bh3,
    float* __restrict__ bt)
{
    const int b = blockIdx.x;
    const int tid = threadIdx.x;

    if (b < PB_EMBH) {
        int gid = b * 256 + tid;
        int row = gid >> 6, c = gid & 63;
        if (c >= 40) return;
        int k0 = c * 8;
        unsigned short vals[8] __attribute__((aligned(16)));
        if (k0 + 7 < 300) {
            const float4 f0 = *reinterpret_cast<const float4*>(emb + (size_t)row * 300 + k0);
            const float4 f1 = *reinterpret_cast<const float4*>(emb + (size_t)row * 300 + k0 + 4);
            unsigned u0 = pk2h(f0.x, f0.y), u1 = pk2h(f0.z, f0.w);
            unsigned u2 = pk2h(f1.x, f1.y), u3 = pk2h(f1.z, f1.w);
            vals[0] = (unsigned short)u0; vals[1] = (unsigned short)(u0 >> 16);
            vals[2] = (unsigned short)u1; vals[3] = (unsigned short)(u1 >> 16);
            vals[4] = (unsigned short)u2; vals[5] = (unsigned short)(u2 >> 16);
            vals[6] = (unsigned short)u3; vals[7] = (unsigned short)(u3 >> 16);
        } else {
#pragma unroll
            for (int jj = 0; jj < 8; ++jj) {
                int k = k0 + jj;
                vals[jj] = (k < 300) ? f2h(emb[(size_t)row * 300 + k]) : (unsigned short)0;
            }
        }
        *reinterpret_cast<uint4*>(embH + (size_t)row * 320 + k0) =
            *reinterpret_cast<const uint4*>(vals);
        return;
    }

    if (b < PB_WHH) {
        int gid = (b - PB_EMBH) * 256 + tid;
        if (gid >= 4 * NT * KCH * 64) return;
        int lane = gid & 63;
        int f = gid >> 6;
        int kc = f % KCH;
        int tIdx = (f / KCH) % NT;
        int d = f / (KCH * NT);
        const float* w = (d == 0) ? whh0 : (d == 1) ? whh1 : (d == 2) ? whh2 : whh3;
        int g = tIdx / GT, j = tIdx % GT;
        int il = j * 16 + (lane & 15);
        int n = g * HDIM + il;
        int kb = kc * 32 + (lane >> 4) * 8;
        unsigned short vals[8] __attribute__((aligned(16)));
#pragma unroll
        for (int jj = 0; jj < 8; ++jj) {
            int k = kb + jj;
            float v = (il < HDIM && k < HDIM) ? w[n * HDIM + k] : 0.f;
            vals[jj] = f2h(v);
        }
        *reinterpret_cast<float4*>(reinterpret_cast<char*>(Bhh) + (size_t)gid * 16) =
            *reinterpret_cast<const float4*>(vals);
        return;
    }

    if (b < PB_BIH) {
        int rel = b - PB_WHH;
        const float* w; unsigned short* Bp; int Kin, KC, base;
        if (rel < 100)      { w = wih0; Bp = BiW0; Kin = 300; KC = KC_W; base = 0; }
        else if (rel < 200) { w = wih1; Bp = BiW1; Kin = 300; KC = KC_W; base = 100; }
        else if (rel < 330) { w = wih2; Bp = BiS0; Kin = 400; KC = KC_S; base = 200; }
        else                { w = wih3; Bp = BiS1; Kin = 400; KC = KC_S; base = 330; }
        int gid = (rel - base) * 256 + tid;
        if (gid >= NTP * KC * 64) return;
        int lane = gid & 63;
        int f = gid >> 6;
        int kc = f % KC;
        int tIdx = f / KC;
        int g = tIdx / GT, j = tIdx % GT;
        int il = j * 16 + (lane & 15);
        int n = g * HDIM + il;
        int kb = kc * 32 + (lane >> 4) * 8;
        unsigned short vals[8] __attribute__((aligned(16)));
#pragma unroll
        for (int jj = 0; jj < 8; ++jj) {
            int k = kb + jj;
            float v = (tIdx < NT && il < HDIM && k < Kin) ? w[n * Kin + k] : 0.f;
            vals[jj] = f2h(v);
        }
        *reinterpret_cast<float4*>(reinterpret_cast<char*>(Bp) + (size_t)gid * 16) =
            *reinterpret_cast<const float4*>(vals);
        return;
    }

    {
        int gid = (b - PB_BIH) * 256 + tid;
        if (gid < NS) {
            int c = 0;
            for (int t = 0; t < TW; ++t) c += (x[gid * TW + t] != 0) ? 1 : 0;
            sl[gid] = c;
            return;
        }
        int g2 = gid - NS;
        if (g2 >= 4 * 624) return;
        int d = g2 / 624, col = g2 % 624;
        int g = col / 208, i = col % 208;
        const float* bi = (d == 0) ? bi0 : (d == 1) ? bi1 : (d == 2) ? bi2 : bi3;
        const float* bh = (d == 0) ? bh0 : (d == 1) ? bh1 : (d == 2) ? bh2 : bh3;
        float v = 0.f;
        if (i < HDIM) v = (g < 2) ? (bi[g * HDIM + i] + bh[g * HDIM + i]) : bi[2 * HDIM + i];
        bt[g2] = v;
    }
}

// ---------------- word-level MFMA GEMM: 64-row blocks, 2/CU ---------------
// revOrd=1 reverses block order so low-t tiles are written LAST (L3-fresh
// for the fwd gru that reads t=0 first).
__global__ __launch_bounds__(512, 4) void gemm_word(
    const unsigned short* __restrict__ embH, const int* __restrict__ idx,
    const unsigned short* __restrict__ Bp,
    const float* __restrict__ bt, unsigned short* __restrict__ gxOut, int revOrd)
{
    __shared__ __align__(16) unsigned short As[64 * 320];  // 40 KB

    const int tid = threadIdx.x;
    const int n_w = tid >> 6, lane = tid & 63;
    const int bm = revOrd ? (gridDim.x - 1 - blockIdx.x) : blockIdx.x;

    {
        const int srow = tid >> 3, q8 = tid & 7;
        int rp = bm * 64 + srow;
        int tok = idx[(rp % NS) * TW + (rp / NS)];
        const unsigned short* src = embH + (size_t)tok * 320;
        const int rx = srow & 7;
        unsigned short* dst = &As[srow * 320];
#pragma unroll
        for (int jj = 0; jj < 5; ++jj) {
            int c = q8 + jj * 8;                    // chunk 0..39
            uint4 v = *reinterpret_cast<const uint4*>(src + c * 8);
            int slot = c ^ rx;
            *reinterpret_cast<uint4*>(dst + slot * 8) = v;
        }
    }
    __syncthreads();

    f32x4 acc[4][5];
#pragma unroll
    for (int i = 0; i < 4; ++i)
#pragma unroll
        for (int j = 0; j < 5; ++j) acc[i][j] = (f32x4){0.f, 0.f, 0.f, 0.f};

    const uint4* bq = reinterpret_cast<const uint4*>(Bp);
    const int q = lane >> 4, r15 = lane & 15;
    const int sx = r15 & 7;

#pragma unroll 2
    for (int kc = 0; kc < KC_W; ++kc) {
        h16x8 ah[4];
        const int slot = (kc * 4 + q) ^ sx;
#pragma unroll
        for (int mt = 0; mt < 4; ++mt)
            ah[mt] = *reinterpret_cast<const h16x8*>(
                &As[(mt * 16 + r15) * 320 + slot * 8]);
        uint4 b[5];
#pragma unroll
        for (int j = 0; j < 5; ++j) {
            int gnt = n_w * 5 + j;
            b[j] = bq[(size_t)(gnt * KC_W + kc) * 64 + lane];
        }
#pragma unroll
        for (int mt = 0; mt < 4; ++mt)
#pragma unroll
            for (int j = 0; j < 5; ++j)
                acc[mt][j] = __builtin_amdgcn_mfma_f32_16x16x32_f16(
                    ah[mt], *reinterpret_cast<const h16x8*>(&b[j]),
                    acc[mt][j], 0, 0, 0);
    }

    float btv[5];
#pragma unroll
    for (int j = 0; j < 5; ++j) {
        int gnt = n_w * 5 + j;
        btv[j] = (gnt < NT) ? bt[gnt * 16 + r15] : 0.f;
    }

#pragma unroll
    for (int mt = 0; mt < 4; ++mt) {
        int gmt = bm * 4 + mt;
#pragma unroll
        for (int j = 0; j < 5; ++j) {
            int gnt = n_w * 5 + j;
            if (gnt < NT) {
                uint2 v;
                v.x = pk2h(acc[mt][j][0] + btv[j], acc[mt][j][1] + btv[j]);
                v.y = pk2h(acc[mt][j][2] + btv[j], acc[mt][j][3] + btv[j]);
                *reinterpret_cast<uint2*>(reinterpret_cast<char*>(gxOut) +
                    ((size_t)(gmt * NT + gnt) * 64 + lane) * 8) = v;
            }
        }
    }
}

// ---------------- sentence-level MFMA GEMM: single-barrier, 64-row --------
// Dual-direction: blocks [0,nF) -> dir0, [nF,grid) -> dir1. Whole 64x448
// A-panel (f32 -> f16 in staging, K padded 416->448) staged with ONE
// barrier, then barrier-free 13-kc MFMA sweep. acc[4][5] like gemm_word.
__global__ __launch_bounds__(512, 4) void gemm_sent(
    const float* __restrict__ Afl, int astride,
    const unsigned short* __restrict__ Bp0, const unsigned short* __restrict__ Bp1,
    const float* __restrict__ bt0, const float* __restrict__ bt1,
    unsigned short* __restrict__ gx0, unsigned short* __restrict__ gx1, int nF)
{
    __shared__ __align__(16) unsigned short As[64 * 448];  // 57,344 B

    const int tid = threadIdx.x;
    const int n_w = tid >> 6, lane = tid & 63;
    const int d = (blockIdx.x >= nF) ? 1 : 0;
    const int bm = d ? (blockIdx.x - nF) : blockIdx.x;
    const unsigned short* Bp = d ? Bp1 : Bp0;
    const float* bt = d ? bt1 : bt0;
    unsigned short* gxOut = d ? gx1 : gx0;

    // ---- stage: 64 rows x 448 halfs (400 live), one barrier ----
    {
        const int srow = tid >> 3, q8 = tid & 7;
        const float* src = Afl + (size_t)(bm * 64 + srow) * astride;
        const int rx = srow & 7;
        unsigned short* dst = &As[srow * 448];
#pragma unroll
        for (int jj = 0; jj < 7; ++jj) {
            int c = q8 + jj * 8;                    // chunk 0..55
            int k0 = c * 8;
            unsigned short vals[8] __attribute__((aligned(16)));
            if (k0 + 7 < 400) {
                const float4 f0 = *reinterpret_cast<const float4*>(src + k0);
                const float4 f1 = *reinterpret_cast<const float4*>(src + k0 + 4);
                unsigned u0 = pk2h(f0.x, f0.y), u1 = pk2h(f0.z, f0.w);
                unsigned u2 = pk2h(f1.x, f1.y), u3 = pk2h(f1.z, f1.w);
                vals[0] = (unsigned short)u0; vals[1] = (unsigned short)(u0 >> 16);
                vals[2] = (unsigned short)u1; vals[3] = (unsigned short)(u1 >> 16);
                vals[4] = (unsigned short)u2; vals[5] = (unsigned short)(u2 >> 16);
                vals[6] = (unsigned short)u3; vals[7] = (unsigned short)(u3 >> 16);
            } else {
#pragma unroll
                for (int e = 0; e < 8; ++e) {
                    int k = k0 + e;
                    vals[e] = (k < 400) ? f2h(src[k]) : (unsigned short)0;
                }
            }
            int slot = c ^ rx;
            *reinterpret_cast<uint4*>(dst + slot * 8) =
                *reinterpret_cast<const uint4*>(vals);
        }
    }
    __syncthreads();

    f32x4 acc[4][5];
#pragma unroll
    for (int i = 0; i < 4; ++i)
#pragma unroll
        for (int j = 0; j < 5; ++j) acc[i][j] = (f32x4){0.f, 0.f, 0.f, 0.f};

    const uint4* bq = reinterpret_cast<const uint4*>(Bp);
    const int q = lane >> 4, r15 = lane & 15;
    const int sx = r15 & 7;

#pragma unroll 2
    for (int kc = 0; kc < KC_S; ++kc) {
        h16x8 ah[4];
        const int slot = (kc * 4 + q) ^ sx;
#pragma unroll
        for (int mt = 0; mt < 4; ++mt)
            ah[mt] = *reinterpret_cast<const h16x8*>(
                &As[(mt * 16 + r15) * 448 + slot * 8]);
        uint4 b[5];
#pragma unroll
        for (int j = 0; j < 5; ++j) {
            int gnt = n_w * 5 + j;
            b[j] = bq[(size_t)(gnt * KC_S + kc) * 64 + lane];
        }
#pragma unroll
        for (int mt = 0; mt < 4; ++mt)
#pragma unroll
            for (int j = 0; j < 5; ++j)
                acc[mt][j] = __builtin_amdgcn_mfma_f32_16x16x32_f16(
                    ah[mt], *reinterpret_cast<const h16x8*>(&b[j]),
                    acc[mt][j], 0, 0, 0);
    }

    float btv[5];
#pragma unroll
    for (int j = 0; j < 5; ++j) {
        int gnt = n_w * 5 + j;
        btv[j] = (gnt < NT) ? bt[gnt * 16 + r15] : 0.f;
    }

#pragma unroll
    for (int mt = 0; mt < 4; ++mt) {
        int gmt = bm * 4 + mt;
#pragma unroll
        for (int j = 0; j < 5; ++j) {
            int gnt = n_w * 5 + j;
            if (gnt < NT) {
                uint2 v;
                v.x = pk2h(acc[mt][j][0] + btv[j], acc[mt][j][1] + btv[j]);
                v.y = pk2h(acc[mt][j][2] + btv[j], acc[mt][j][3] + btv[j]);
                *reinterpret_cast<uint2*>(reinterpret_cast<char*>(gxOut) +
                    ((size_t)(gmt * NT + gnt) * 64 + lane) * 8) = v;
            }
        }
    }
}

// ---------------- word GRU: 7 waves x 2 tiles/wave (r20 body) -------------
__global__ __launch_bounds__(448, 2) void gru_word(
    const unsigned short* __restrict__ gxA, const unsigned short* __restrict__ gxB,
    const unsigned short* __restrict__ Bp, int dirBase0, int dirBase1,
    const float* __restrict__ bh0, const float* __restrict__ bh1,
    const int* __restrict__ lens, float* __restrict__ pool,
    int S, int T, int poolMode, int nF)
{
    __shared__ __align__(16) unsigned short hh[2][16 * HSTR];  // 14.5 KB

    const int dsel = (blockIdx.x >= nF) ? 1 : 0;
    const int lb = dsel ? (blockIdx.x - nF) : blockIdx.x;
    const unsigned short* gx = dsel ? gxB : gxA;
    const int dirBase = dsel ? dirBase1 : dirBase0;
    const float* bh = dsel ? bh1 : bh0;
    const int dirOff = dsel ? HDIM : 0;
    const int rev = dsel;

    const int tid = threadIdx.x;
    const int w = tid >> 6, lane = tid & 63;
    const int quad = lane >> 4, c = lane & 15;
    const int row0 = lb * 16;
    const int j0 = 2 * w, j1 = 2 * w + 1;
    const int i0 = j0 * 16 + c, i1 = j1 * 16 + c;
    const bool t1v = (j1 < GT);             // wave-uniform
    const bool iv0 = (i0 < HDIM), iv1 = t1v && (i1 < HDIM);

    for (int p = tid; p < 2 * 16 * HSTR; p += 448)
        hh[0][p] = 0;                        // zero both buffers (flat)
    __syncthreads();

    const float bhn0 = iv0 ? bh[2 * HDIM + i0] : 0.f;
    const float bhn1 = iv1 ? bh[2 * HDIM + i1] : 0.f;

    int slen[4];
    float hr0[4], hr1[4], pa0[4], pa1[4];
#pragma unroll
    for (int rg = 0; rg < 4; ++rg) {
        int L = lens[row0 + quad * 4 + rg];
        if (L < 0) L = 0;
        if (L > T) L = T;
        slen[rg] = L;
        hr0[rg] = 0.f; hr1[rg] = 0.f; pa0[rg] = 0.f; pa1[rg] = 0.f;
    }

    const float4* Bq = reinterpret_cast<const float4*>(Bp);
    h16x8 bfr[2][3][KCH];
#pragma unroll
    for (int g = 0; g < 3; ++g)
#pragma unroll
        for (int kc = 0; kc < KCH; ++kc) {
            {
                int fidx = (dirBase + g * GT + j0) * KCH + kc;
                float4 raw = Bq[(size_t)fidx * 64 + lane];
                bfr[0][g][kc] = *reinterpret_cast<h16x8*>(&raw);
            }
            if (t1v) {
                int fidx = (dirBase + g * GT + j1) * KCH + kc;
                float4 raw = Bq[(size_t)fidx * 64 + lane];
                bfr[1][g][kc] = *reinterpret_cast<h16x8*>(&raw);
            }
        }

    const char* gxb = reinterpret_cast<const char*>(gx);
    const int am = c * HSTR + quad * 8;
    const int SG = S >> 4;
    const int hw0 = (quad * 4) * HSTR + i0;
    const int hw1 = (quad * 4) * HSTR + i1;
    const int dstep = (rev ? -SG : SG) * NT * 512;
    int boff;
    {
        const int t0 = rev ? (T - 1) : 0;
        boff = ((t0 * SG + lb) * NT) * 512 + lane * 8;
    }
    __syncthreads();

    for (int ts = 0; ts < T; ++ts) {
        const int t = rev ? (T - 1 - ts) : ts;
        const int cur = ts & 1, nxt = cur ^ 1;

        // gx for this step (issued at step start; latency overlaps MFMA)
        uint2 gx0[3], gx1[3];
#pragma unroll
        for (int g = 0; g < 3; ++g) {
            gx0[g] = *reinterpret_cast<const uint2*>(gxb + boff + (g * GT + j0) * 512);
            if (t1v)
                gx1[g] = *reinterpret_cast<const uint2*>(gxb + boff + (g * GT + j1) * 512);
        }
        boff += dstep;

        f32x4 a00 = (f32x4){0.f, 0.f, 0.f, 0.f}, a01 = a00, a02 = a00;
        f32x4 a10 = a00, a11 = a00, a12 = a00;
#pragma unroll
        for (int kc = 0; kc < KCH; ++kc) {
            h16x8 ah = *reinterpret_cast<const h16x8*>(&hh[cur][am + kc * 32]);
            a00 = __builtin_amdgcn_mfma_f32_16x16x32_f16(ah, bfr[0][0][kc], a00, 0, 0, 0);
            a01 = __builtin_amdgcn_mfma_f32_16x16x32_f16(ah, bfr[0][1][kc], a01, 0, 0, 0);
            a02 = __builtin_amdgcn_mfma_f32_16x16x32_f16(ah, bfr[0][2][kc], a02, 0, 0, 0);
            if (t1v) {
                a10 = __builtin_amdgcn_mfma_f32_16x16x32_f16(ah, bfr[1][0][kc], a10, 0, 0, 0);
                a11 = __builtin_amdgcn_mfma_f32_16x16x32_f16(ah, bfr[1][1][kc], a11, 0, 0, 0);
                a12 = __builtin_amdgcn_mfma_f32_16x16x32_f16(ah, bfr[1][2][kc], a12, 0, 0, 0);
            }
        }

        if (iv0) {
#pragma unroll
            for (int rg = 0; rg < 4; ++rg) {
                float r = sigf(hfsel(gx0[0], rg) + a00[rg]);
                float z = sigf(hfsel(gx0[1], rg) + a01[rg]);
                float n = tanh_fast(hfsel(gx0[2], rg) + r * (a02[rg] + bhn0));
                float hnew = n + z * (hr0[rg] - n);
                hr0[rg] = hnew;
                hh[nxt][hw0 + rg * HSTR] = f2h(hnew);
                pa0[rg] += (t < slen[rg]) ? hnew : 0.f;
            }
        }
        if (iv1) {
#pragma unroll
            for (int rg = 0; rg < 4; ++rg) {
                float r = sigf(hfsel(gx1[0], rg) + a10[rg]);
                float z = sigf(hfsel(gx1[1], rg) + a11[rg]);
                float n = tanh_fast(hfsel(gx1[2], rg) + r * (a12[rg] + bhn1));
                float hnew = n + z * (hr1[rg] - n);
                hr1[rg] = hnew;
                hh[nxt][hw1 + rg * HSTR] = f2h(hnew);
                pa1[rg] += (t < slen[rg]) ? hnew : 0.f;
            }
        }
        __syncthreads();
    }

#pragma unroll
    for (int rg = 0; rg < 4; ++rg) {
        int sg = row0 + quad * 4 + rg;
        int L = slen[rg];
        int prow = poolMode ? ((sg % 10) * ND + sg / 10) : sg;
        float inv = (L > 0) ? 1.f / (float)L : 0.f;
        if (iv0) pool[(size_t)prow * 400 + dirOff + i0] = pa0[rg] * inv;
        if (iv1) pool[(size_t)prow * 400 + dirOff + i1] = pa1[rg] * inv;
    }
}

// ---------------- sentence GRU: proven 13-wave kernel ---------------------
__global__ __launch_bounds__(832, 4) void gru_fused(
    const unsigned short* __restrict__ gxA, const unsigned short* __restrict__ gxB,
    const unsigned short* __restrict__ Bp, int dirBase0, int dirBase1,
    const float* __restrict__ bh0, const float* __restrict__ bh1,
    const int* __restrict__ lens, float* __restrict__ pool,
    int S, int T, int poolMode, int nF)
{
    __shared__ __align__(16) unsigned short hh[2][16 * HSTR];  // 14.5 KB

    const int dsel = (blockIdx.x >= nF) ? 1 : 0;
    const int lb = dsel ? (blockIdx.x - nF) : blockIdx.x;
    const unsigned short* gx = dsel ? gxB : gxA;
    const int dirBase = dsel ? dirBase1 : dirBase0;
    const float* bh = dsel ? bh1 : bh0;
    const int dirOff = dsel ? HDIM : 0;
    const int rev = dsel;

    const int tid = threadIdx.x;
    const int w = tid >> 6, lane = tid & 63;
    const int quad = lane >> 4, c = lane & 15;
    const int row0 = lb * 16;
    const int i = w * 16 + c;
    const bool iv = (i < HDIM);

    for (int p = tid; p < 16 * HSTR; p += 832) { hh[0][p] = 0; hh[1][p] = 0; }
    __syncthreads();

    const float bhn = iv ? bh[2 * HDIM + i] : 0.f;

    int slen[4];
    float hreg[4], pacc[4];
#pragma unroll
    for (int rg = 0; rg < 4; ++rg) {
        int L = lens[row0 + quad * 4 + rg];
        if (L < 0) L = 0;
        if (L > T) L = T;
        slen[rg] = L;
        hreg[rg] = 0.f; pacc[rg] = 0.f;
    }

    const float4* Bq = reinterpret_cast<const float4*>(Bp);
    h16x8 bfr[3][7];
#pragma unroll
    for (int g = 0; g < 3; ++g)
#pragma unroll
        for (int kc = 0; kc < KCH; ++kc) {
            int fidx = (dirBase + g * GT + w) * KCH + kc;
            float4 raw = Bq[(size_t)fidx * 64 + lane];
            bfr[g][kc] = *reinterpret_cast<h16x8*>(&raw);
        }

    const char* gxb = reinterpret_cast<const char*>(gx);
    const int am = c * HSTR + quad * 8;
    const int SG = S >> 4;
    const int hw0 = (quad * 4) * HSTR + i;
    const int GSTR = GT * 64 * 8;
    const int dstep = (rev ? -SG : SG) * NT * 512;
    __syncthreads();

    uint2 gxv[3], gnx[3];
    int boff;
    {
        const int t0 = rev ? (T - 1) : 0;
        boff = (((t0 * SG + lb) * NT + w) * 64 + lane) * 8;
#pragma unroll
        for (int g = 0; g < 3; ++g)
            gxv[g] = *reinterpret_cast<const uint2*>(gxb + boff + g * GSTR);
        boff += dstep;
    }

    for (int ts = 0; ts < T; ++ts) {
        const int t = rev ? (T - 1 - ts) : ts;
        const int cur = ts & 1, nxt = cur ^ 1;

        if (ts + 1 < T) {
#pragma unroll
            for (int g = 0; g < 3; ++g)
                gnx[g] = *reinterpret_cast<const uint2*>(gxb + boff + g * GSTR);
            boff += dstep;
        }

        f32x4 a0 = (f32x4){0.f, 0.f, 0.f, 0.f}, a1 = a0, a2 = a0;
#pragma unroll
        for (int kc = 0; kc < KCH; ++kc) {
            h16x8 ah = *reinterpret_cast<const h16x8*>(&hh[cur][am + kc * 32]);
            a0 = __builtin_amdgcn_mfma_f32_16x16x32_f16(ah, bfr[0][kc], a0, 0, 0, 0);
            a1 = __builtin_amdgcn_mfma_f32_16x16x32_f16(ah, bfr[1][kc], a1, 0, 0, 0);
            a2 = __builtin_amdgcn_mfma_f32_16x16x32_f16(ah, bfr[2][kc], a2, 0, 0, 0);
        }

        if (iv) {
#pragma unroll
            for (int rg = 0; rg < 4; ++rg) {
                float xr = hfsel(gxv[0], rg);
                float xz = hfsel(gxv[1], rg);
                float xn = hfsel(gxv[2], rg);
                float r = sigf(xr + a0[rg]);
                float z = sigf(xz + a1[rg]);
                float n = tanh_fast(xn + r * (a2[rg] + bhn));
                float hnew = n + z * (hreg[rg] - n);
                hreg[rg] = hnew;
                hh[nxt][hw0 + rg * HSTR] = f2h(hnew);
                pacc[rg] += (t < slen[rg]) ? hnew : 0.f;
            }
        }
        __syncthreads();
        if (ts + 1 < T) {
#pragma unroll
            for (int g = 0; g < 3; ++g) gxv[g] = gnx[g];
        }
    }

    if (iv) {
#pragma unroll
        for (int rg = 0; rg < 4; ++rg) {
            int sg = row0 + quad * 4 + rg;
            int L = slen[rg];
            float v = (L > 0) ? pacc[rg] / (float)L : 0.f;
            int prow = poolMode ? ((sg % 10) * ND + sg / 10) : sg;
            pool[(size_t)prow * 400 + dirOff + i] = v;
        }
    }
}

// ---------------- heads: 256 blocks x 1 wave ----------------
__global__ __launch_bounds__(64) void head_kernel(
    const float* __restrict__ d_pool, const int* __restrict__ doc_lens,
    const float* __restrict__ doc_w, const float* __restrict__ doc_b,
    const float* __restrict__ sent_w, const float* __restrict__ sent_b,
    float* __restrict__ out)
{
    const int d = blockIdx.x;
    const int lane = threadIdx.x;

    int part = 0;
#pragma unroll
    for (int rep = 0; rep < 4; ++rep) {
        int j = lane + rep * 64;
        int v = doc_lens[j];
        v = (v < 0) ? 0 : (v > DTR ? DTR : v);
        if (j < d) part += v;
    }
#pragma unroll
    for (int off = 32; off; off >>= 1) part += __shfl_down(part, off);
    int soff = __shfl(part, 0);

    int dl = doc_lens[d];
    dl = (dl < 0) ? 0 : (dl > DTR ? DTR : dl);
    const float* dv = d_pool + (size_t)d * 400;

    for (int o = 0; o <= dl; ++o) {
        const float* wrow = (o == 0) ? doc_w : sent_w + (o - 1) * 400;
        float s = 0.f;
        for (int f = lane; f < 400; f += 64) s += dv[f] * wrow[f];
#pragma unroll
        for (int off = 32; off; off >>= 1) s += __shfl_down(s, off);
        if (lane == 0) {
            float bias = (o == 0) ? doc_b[0] : sent_b[o - 1];
            out[(o == 0) ? d : (ND + soff + (o - 1))] = sigf(s + bias);
        }
    }
}

// --------------------------------------------------------------------------
extern "C" void kernel_launch(void* const* d_in, const int* in_sizes, int n_in,
                              void* d_out, int out_size, void* d_ws, size_t ws_size,
                              hipStream_t stream) {
    const int*   x        = (const int*)d_in[0];
    const int*   doc_lens = (const int*)d_in[2];
    const float* emb      = (const float*)d_in[3];
    const float* wf_ih = (const float*)d_in[4];
    const float* wf_hh = (const float*)d_in[5];
    const float* wf_bi = (const float*)d_in[6];
    const float* wf_bh = (const float*)d_in[7];
    const float* wb_ih = (const float*)d_in[8];
    const float* wb_hh = (const float*)d_in[9];
    const float* wb_bi = (const float*)d_in[10];
    const float* wb_bh = (const float*)d_in[11];
    const float* sf_ih = (const float*)d_in[12];
    const float* sf_hh = (const float*)d_in[13];
    const float* sf_bi = (const float*)d_in[14];
    const float* sf_bh = (const float*)d_in[15];
    const float* sb_ih = (const float*)d_in[16];
    const float* sb_hh = (const float*)d_in[17];
    const float* sb_bi = (const float*)d_in[18];
    const float* sb_bh = (const float*)d_in[19];
    const float* doc_w  = (const float*)d_in[20];
    const float* doc_b  = (const float*)d_in[21];
    const float* sent_w = (const float*)d_in[22];
    const float* sent_b = (const float*)d_in[23];

    const size_t GXSZ = 159744000;   // full-range gx
    char* ws = (char*)d_ws;
    const size_t base = GXSZ;

    unsigned short* gxF  = (unsigned short*)(ws);
    unsigned short* gxS0 = (unsigned short*)(ws);            // sentence slices
    unsigned short* gxS1 = (unsigned short*)(ws + 8000000);
    float* s_in   = (float*)(ws + base);                       // 4,096,256 B
    float* dpool  = (float*)(ws + base + 4096256);             // 409,600 B
    int*   sl     = (int*)(ws + base + 4096256 + 409600);      // 10,240 B
    unsigned short* Bhh  = (unsigned short*)(ws + base + 4096256 + 409600 + 10240);
    unsigned short* BiW0 = (unsigned short*)((char*)Bhh + 1118208);
    unsigned short* BiW1 = BiW0 + NTP * KC_W * 64 * 8;
    unsigned short* BiS0 = (unsigned short*)((char*)BiW0 + 819200);
    unsigned short* BiS1 = BiS0 + NTP * KC_S * 64 * 8;
    float* bt     = (float*)((char*)BiS0 + 1064960);
    unsigned short* embH = (unsigned short*)((char*)bt + 9984);   // 32,000,000

    prepack_all<<<PB_ALL, 256, 0, stream>>>(
        emb, embH,
        wf_hh, wb_hh, sf_hh, sb_hh, Bhh,
        wf_ih, wb_ih, sf_ih, sb_ih, BiW0, BiW1, BiS0, BiS1,
        x, sl,
        wf_bi, wf_bh, wb_bi, wb_bh, sf_bi, sf_bh, sb_bi, sb_bh, bt);

    // word level, sequential directions
    gemm_word<<<2000, 512, 0, stream>>>(embH, x, BiW0, bt + 0, gxF, 1);   // fwd: low t last
    gru_word<<<160, 448, 0, stream>>>(
        gxF, gxF, Bhh, 0 * NT, 1 * NT, wf_bh, wb_bh, sl, s_in, NS, TW, 1, 160);
    gemm_word<<<2000, 512, 0, stream>>>(embH, x, BiW1, bt + 624, gxF, 0); // bwd: high t last
    gru_word<<<160, 448, 0, stream>>>(
        gxF, gxF, Bhh, 0 * NT, 1 * NT, wf_bh, wb_bh, sl, s_in, NS, TW, 1, 0);

    // sentence level: direction-fused, single-barrier 64-row gemm
    gemm_sent<<<80, 512, 0, stream>>>(
        s_in, 400, BiS0, BiS1, bt + 2 * 624, bt + 3 * 624, gxS0, gxS1, 40);
    gru_fused<<<32, 832, 0, stream>>>(
        gxS0, gxS1, Bhh, 2 * NT, 3 * NT, sf_bh, sb_bh, doc_lens, dpool, ND, DTR, 0, 16);

    head_kernel<<<ND, 64, 0, stream>>>(dpool, doc_lens, doc_w, doc_b, sent_w, sent_b, (float*)d_out);
}